// Round 5
// baseline (64.837 us; speedup 1.0000x reference)
//
#include <hip/hip_runtime.h>

typedef float floatx4 __attribute__((ext_vector_type(4)));

struct c32 { float re, im; };
__device__ __forceinline__ c32 cmul(c32 a, c32 b) {
    return { a.re * b.re - a.im * b.im, a.re * b.im + a.im * b.re };
}

// U = Rz(tz) @ Ry(ty) @ Rx(tx), written as 8 floats:
// [U00.re,U00.im, U01.re,U01.im, U10.re,U10.im, U11.re,U11.im]
__device__ __forceinline__ void compute_U(float tx, float ty, float tz, float* u) {
    float cx, sx, cy, sy, cz, sz;
    sincosf(0.5f * tx, &sx, &cx);
    sincosf(0.5f * ty, &sy, &cy);
    sincosf(0.5f * tz, &sz, &cz);
    c32 m00 = {  cy * cx,  sy * sx };
    c32 m01 = { -sy * cx, -cy * sx };
    c32 m10 = {  sy * cx, -cy * sx };
    c32 m11 = {  cy * cx, -sy * sx };
    c32 ez  = { cz, -sz };
    c32 ezc = { cz,  sz };
    c32 U00 = cmul(ez,  m00), U01 = cmul(ez,  m01);
    c32 U10 = cmul(ezc, m10), U11 = cmul(ezc, m11);
    u[0] = U00.re; u[1] = U00.im; u[2] = U01.re; u[3] = U01.im;
    u[4] = U10.re; u[5] = U10.im; u[6] = U11.re; u[7] = U11.im;
}

__device__ __forceinline__ floatx4 apply2(const floatx4 re, const floatx4 im,
                                          const float* ua, const float* ub) {
    floatx4 w;
    w.x = re.x * ua[0] - im.x * ua[1] + re.y * ua[4] - im.y * ua[5];
    w.y = re.x * ua[2] - im.x * ua[3] + re.y * ua[6] - im.y * ua[7];
    w.z = re.z * ub[0] - im.z * ub[1] + re.w * ub[4] - im.w * ub[5];
    w.w = re.z * ub[2] - im.z * ub[3] + re.w * ub[6] - im.w * ub[7];
    return w;
}

// Block owns a 512-wide n-slice (256 threads x 2 pairs each), iterates over a
// chunk of the batch dim, 4 b-values per iteration with all loads issued
// before compute/store (MLP). U lives in registers, computed once per thread.
// Output = real part only: out[(b*N + n)*2 + k].
__global__ __launch_bounds__(256) void apply_rows_kernel(
        const float* __restrict__ sre, const float* __restrict__ sim,
        const float* __restrict__ tx, const float* __restrict__ ty,
        const float* __restrict__ tz,
        float* __restrict__ out, int N, int B,
        int blocks_per_row, int b_per_chunk) {
    const int row_blk = blockIdx.x % blocks_per_row;
    const int chunk   = blockIdx.x / blocks_per_row;
    const int n0 = row_blk * (blockDim.x * 2) + threadIdx.x * 2;

    float ua[8], ub[8];
    compute_U(tx[n0],     ty[n0],     tz[n0],     ua);
    compute_U(tx[n0 + 1], ty[n0 + 1], tz[n0 + 1], ub);

    const int b_start = chunk * b_per_chunk;
    const int b_end   = (b_start + b_per_chunk < B) ? (b_start + b_per_chunk) : B;
    const long long rowstride = (long long)N * 2;

    int b = b_start;
    for (; b + 4 <= b_end; b += 4) {
        const long long base = (long long)b * rowstride + (long long)n0 * 2;
        floatx4 re0, re1, re2, re3, im0, im1, im2, im3;
        re0 = *reinterpret_cast<const floatx4*>(sre + base);
        re1 = *reinterpret_cast<const floatx4*>(sre + base + rowstride);
        re2 = *reinterpret_cast<const floatx4*>(sre + base + 2 * rowstride);
        re3 = *reinterpret_cast<const floatx4*>(sre + base + 3 * rowstride);
        im0 = *reinterpret_cast<const floatx4*>(sim + base);
        im1 = *reinterpret_cast<const floatx4*>(sim + base + rowstride);
        im2 = *reinterpret_cast<const floatx4*>(sim + base + 2 * rowstride);
        im3 = *reinterpret_cast<const floatx4*>(sim + base + 3 * rowstride);
        floatx4 w0 = apply2(re0, im0, ua, ub);
        floatx4 w1 = apply2(re1, im1, ua, ub);
        floatx4 w2 = apply2(re2, im2, ua, ub);
        floatx4 w3 = apply2(re3, im3, ua, ub);
        __builtin_nontemporal_store(w0, reinterpret_cast<floatx4*>(out + base));
        __builtin_nontemporal_store(w1, reinterpret_cast<floatx4*>(out + base + rowstride));
        __builtin_nontemporal_store(w2, reinterpret_cast<floatx4*>(out + base + 2 * rowstride));
        __builtin_nontemporal_store(w3, reinterpret_cast<floatx4*>(out + base + 3 * rowstride));
    }
    for (; b < b_end; ++b) {
        const long long base = (long long)b * rowstride + (long long)n0 * 2;
        const floatx4 re = *reinterpret_cast<const floatx4*>(sre + base);
        const floatx4 im = *reinterpret_cast<const floatx4*>(sim + base);
        floatx4 w = apply2(re, im, ua, ub);
        __builtin_nontemporal_store(w, reinterpret_cast<floatx4*>(out + base));
    }
}

// Fallback (general shapes): one thread-iter = 2 consecutive pairs, U recomputed.
__global__ __launch_bounds__(256) void apply_generic_kernel(
        const float* __restrict__ sre, const float* __restrict__ sim,
        const float* __restrict__ tx, const float* __restrict__ ty,
        const float* __restrict__ tz,
        float* __restrict__ out, int N, long long n_threads_total) {
    const long long stride = (long long)gridDim.x * blockDim.x;
    for (long long t = (long long)blockIdx.x * blockDim.x + threadIdx.x;
         t < n_threads_total; t += stride) {
        const long long p = t * 2;
        const floatx4 re = *reinterpret_cast<const floatx4*>(sre + p * 2);
        const floatx4 im = *reinterpret_cast<const floatx4*>(sim + p * 2);
        const int n0 = (int)(p % N);
        float ua[8], ub[8];
        compute_U(tx[n0],     ty[n0],     tz[n0],     ua);
        compute_U(tx[n0 + 1], ty[n0 + 1], tz[n0 + 1], ub);
        floatx4 w = apply2(re, im, ua, ub);
        *reinterpret_cast<floatx4*>(out + p * 2) = w;
    }
}

extern "C" void kernel_launch(void* const* d_in, const int* in_sizes, int n_in,
                              void* d_out, int out_size, void* d_ws, size_t ws_size,
                              hipStream_t stream) {
    const float* sre = (const float*)d_in[0];
    const float* sim = (const float*)d_in[1];
    const float* tx  = (const float*)d_in[2];
    const float* ty  = (const float*)d_in[3];
    const float* tz  = (const float*)d_in[4];
    float* out = (float*)d_out;

    const int N = in_sizes[2];                          // n_qubits = 4096
    const long long n_floats = (long long)in_sizes[0];  // B*N*2
    const long long n_pairs  = n_floats / 2;            // B*N
    const int B = (int)(n_pairs / N);
    const int block = 256;
    const int pairs_per_block = block * 2;              // 512

    if ((N % pairs_per_block) == 0 && (long long)B * N == n_pairs) {
        const int blocks_per_row = N / pairs_per_block; // 8 at N=4096
        int b_chunks = 2048 / blocks_per_row;
        if (b_chunks < 1) b_chunks = 1;
        if (b_chunks > B) b_chunks = B;
        int b_per_chunk = (B + b_chunks - 1) / b_chunks;
        b_per_chunk = (b_per_chunk + 3) & ~3;           // multiple of 4
        b_chunks = (B + b_per_chunk - 1) / b_per_chunk;
        const int grid = blocks_per_row * b_chunks;
        apply_rows_kernel<<<grid, block, 0, stream>>>(
            sre, sim, tx, ty, tz, out, N, B, blocks_per_row, b_per_chunk);
    } else {
        const long long n_threads = n_pairs / 2;
        long long blocks_needed = (n_threads + block - 1) / block;
        const int grid = (int)(blocks_needed < 2048 ? blocks_needed : 2048);
        apply_generic_kernel<<<grid, block, 0, stream>>>(
            sre, sim, tx, ty, tz, out, N, n_threads);
    }
}